// Round 9
// baseline (543.790 us; speedup 1.0000x reference)
//
#include <hip/hip_runtime.h>
#include <hip/hip_bf16.h>
#include <cstdint>
#include <cstddef>

// ---------------------------------------------------------------------------
// MCA bilinear-attention fusion on MI355X (gfx950), bf16 MFMA pipeline.
//   kconvP/kconvA: f32 weights -> bf16 in MFMA-fragment order (ws)
//   kproj : o = l2norm(X^T @ proj)           -> ws (bf16, n,h,t,dh)
//   kmatA : A = o_rgb @ atte_w               -> ws (bf16)
//   kflash: two flash passes (row/col softmax of att), no-max softmax,
//           fused gelu + residual + tanh epilogue -> d_out (f32)
//
// R7 (champion structure): 4 waves/block, 32 q-rows/wave (rg=2 sharing),
//     K+V LDS-staged, swapped QK^T + in-register P: 306us kflash.
// R8: 8 waves / 16 q-rows (occupancy 2x, sharing 1x): 418us REGRESSION ->
//     fragment sharing dominates occupancy.  Reverted to R7 geometry.
// R9: R7 is DMA-bound (32KB/block-tile staged; barrier exposes DMA-compute
//     gap; ~11.5K cyc/tile vs ~620 MFMA).  Halve the DMA: K read DIRECT
//     from global/L2 in QK^T (proven correct in R6 at 124 VGPR), with the
//     R6 bug fixed: K loads are issued AND consumed BEFORE the V-DMA is
//     issued (sched_barrier-pinned), so kf waits never drain the V
//     prefetch; V-DMA then hides under softmax+PV.  K LDS staging, its
//     ds_reads and its 8.4M bank conflicts all deleted; LDS 64->32KB.
// ---------------------------------------------------------------------------

typedef __bf16 bf16_t;
typedef bf16_t bf16x4 __attribute__((ext_vector_type(4)));
typedef bf16_t bf16x8 __attribute__((ext_vector_type(8)));
typedef float  f32x4  __attribute__((ext_vector_type(4)));

#define DEV static __device__ __forceinline__

constexpr int Tdim = 1024;   // t
constexpr int Ddim = 1024;   // d
constexpr int DH   = 256;    // d/h
constexpr int NH   = 4;      // heads
constexpr int NB   = 16;     // batch n

DEV f32x4 mm16(bf16x8 a, bf16x8 b, f32x4 c) {
  return __builtin_amdgcn_mfma_f32_16x16x32_bf16(a, b, c, 0, 0, 0);
}

DEV bf16x8 cmb(bf16x4 lo, bf16x4 hi) {
  return __builtin_shufflevector(lo, hi, 0, 1, 2, 3, 4, 5, 6, 7);
}

// Hardware transpose read from a [K][16] bf16 chunk: lane l gets k = 4g+j (lo)
// and k = 16+4g+j (hi, offset:512B) of column (l&15).  kappa_tr(g,i).
DEV void tr_pair(const bf16_t* base, int lane, bf16x4& lo, bf16x4& hi) {
  uint32_t a = (uint32_t)(uintptr_t)base + (uint32_t)(lane * 8);
  asm volatile("ds_read_b64_tr_b16 %0, %2\n\t"
               "ds_read_b64_tr_b16 %1, %2 offset:512"
               : "=v"(lo), "=v"(hi)
               : "v"(a));
}

DEV void lgkm0_fence() {
  asm volatile("s_waitcnt lgkmcnt(0)" ::: "memory");
  __builtin_amdgcn_sched_barrier(0);
}

// async global -> LDS, 16B per lane; lds dest must be wave-uniform base.
DEV void gload16(const void* g, void* l) {
  __builtin_amdgcn_global_load_lds(
      (const __attribute__((address_space(1))) uint32_t*)g,
      (__attribute__((address_space(3))) uint32_t*)l, 16, 0, 0);
}

// ---------------------------------------------------------------------------
// kconvP: rgb_proj/flow_proj f32 -> bf16 fragments in kappa_tr order.
// Wl[mod][h][kb(32)][nf(16)][g(4)][c(16)][i(8)], k = kb*32 + tr(g,i).
// 262144 threads, 8 elems each.
// ---------------------------------------------------------------------------
__global__ void kconvP(const float* __restrict__ rgbp,
                       const float* __restrict__ flowp,
                       bf16_t* __restrict__ Wl) {
  int oc = blockIdx.x * 256 + threadIdx.x;          // 0..262143
  int c = oc & 15, g = (oc >> 4) & 3, nf = (oc >> 6) & 15;
  int kb = (oc >> 10) & 31, h = (oc >> 15) & 3, mod = oc >> 17;
  const float* src = (mod ? flowp : rgbp) + (size_t)h * Ddim * DH + nf * 16 + c;
  bf16x8 v;
#pragma unroll
  for (int i = 0; i < 8; ++i) {
    int k = kb * 32 + ((i < 4) ? 4 * g + i : 12 + 4 * g + i);
    v[i] = (bf16_t)src[(size_t)k * DH];
  }
  *(bf16x8*)(Wl + (size_t)oc * 8) = v;
}

// ---------------------------------------------------------------------------
// kconvA: atte_w f32 -> bf16 fragments in kappa' (contiguous) order.
// Wa[h][kb(8)][nf(16)][g(4)][c(16)][i(8)], k = kb*32 + 8g + i.
// 32768 threads.
// ---------------------------------------------------------------------------
__global__ void kconvA(const float* __restrict__ attw, bf16_t* __restrict__ Wa) {
  int oc = blockIdx.x * 256 + threadIdx.x;          // 0..32767
  int c = oc & 15, g = (oc >> 4) & 3, nf = (oc >> 6) & 15;
  int kb = (oc >> 10) & 7, h = oc >> 13;
  const float* src = attw + (size_t)h * DH * DH + nf * 16 + c;
  bf16x8 v;
#pragma unroll
  for (int i = 0; i < 8; ++i) {
    int k = kb * 32 + 8 * g + i;
    v[i] = (bf16_t)src[(size_t)k * DH];
  }
  *(bf16x8*)(Wa + (size_t)oc * 8) = v;
}

// ---------------------------------------------------------------------------
// kproj: o = l2norm(X^T @ proj).  grid (16, 4, 32) z = nn*2+mod, block 256.
// A (X^T tile) via chunked LDS + tr-read; W fragments direct from global.
// ---------------------------------------------------------------------------
__global__ __launch_bounds__(256, 4)
void kproj(const float* __restrict__ rgb, const float* __restrict__ flow,
           const bf16_t* __restrict__ Wl,
           bf16_t* __restrict__ o_rgb, bf16_t* __restrict__ o_flow) {
  const int t0  = blockIdx.x * 64;
  const int h   = blockIdx.y;
  const int nn  = blockIdx.z >> 1;
  const int mod = blockIdx.z & 1;
  const float* X = (mod ? flow : rgb) + (size_t)nn * Ddim * Tdim + t0;
  const bf16_t* Wb = Wl + (size_t)(mod * NH + h) * 32 * 8192;
  bf16_t* O = (mod ? o_flow : o_rgb) + (size_t)(nn * NH + h) * Tdim * DH;

  __shared__ __align__(128) bf16_t Ach[4 * 512];   // [tchunk][k=32][16]
  __shared__ float sq[4][64];

  const int tid = threadIdx.x;
  const int lane = tid & 63, wv = tid >> 6;
  const int g = lane >> 4, ln = lane & 15;

  f32x4 acc[4][4] = {};   // [mi][f]: rows t0+mi*16+4g+r, cols wv*64+f*16+ln
  const int akk = tid >> 3, atoff = (tid & 7) * 8;

  for (int kb = 0; kb < 32; ++kb) {
    {  // stage A tile (column-major in X), convert to bf16, chunked
      const float* srcx = X + (size_t)(kb * 32 + akk) * Tdim + atoff;
      float4 f0 = *(const float4*)srcx;
      float4 f1 = *(const float4*)(srcx + 4);
      bf16x8 v = {(bf16_t)f0.x, (bf16_t)f0.y, (bf16_t)f0.z, (bf16_t)f0.w,
                  (bf16_t)f1.x, (bf16_t)f1.y, (bf16_t)f1.z, (bf16_t)f1.w};
      *(bf16x8*)&Ach[(atoff >> 4) * 512 + akk * 16 + (atoff & 15)] = v;
    }
    __syncthreads();

    bf16x4 alo[4], ahi[4];
#pragma unroll
    for (int mi = 0; mi < 4; ++mi) tr_pair(&Ach[mi * 512], lane, alo[mi], ahi[mi]);
    bf16x8 wf[4];
    const bf16_t* wt = Wb + (size_t)kb * 8192 + (wv * 4) * 512 + lane * 8;
#pragma unroll
    for (int f = 0; f < 4; ++f) wf[f] = *(const bf16x8*)(wt + f * 512);
    lgkm0_fence();
#pragma unroll
    for (int mi = 0; mi < 4; ++mi) {
      bf16x8 a = cmb(alo[mi], ahi[mi]);
#pragma unroll
      for (int f = 0; f < 4; ++f) acc[mi][f] = mm16(a, wf[f], acc[mi][f]);
    }
    __syncthreads();
  }

  // row L2 norms
  float inv[4][4];
#pragma unroll
  for (int mi = 0; mi < 4; ++mi)
#pragma unroll
    for (int r = 0; r < 4; ++r) {
      float s = 0.f;
#pragma unroll
      for (int f = 0; f < 4; ++f) { float v = acc[mi][f][r]; s += v * v; }
      s += __shfl_xor(s, 1); s += __shfl_xor(s, 2);
      s += __shfl_xor(s, 4); s += __shfl_xor(s, 8);
      if (ln == 0) sq[wv][mi * 16 + 4 * g + r] = s;
    }
  __syncthreads();
#pragma unroll
  for (int mi = 0; mi < 4; ++mi)
#pragma unroll
    for (int r = 0; r < 4; ++r) {
      int rl = mi * 16 + 4 * g + r;
      float s = sq[0][rl] + sq[1][rl] + sq[2][rl] + sq[3][rl];
      inv[mi][r] = 1.0f / fmaxf(sqrtf(s), 1e-12f);
    }
#pragma unroll
  for (int mi = 0; mi < 4; ++mi)
#pragma unroll
    for (int f = 0; f < 4; ++f)
#pragma unroll
      for (int r = 0; r < 4; ++r)
        O[(size_t)(t0 + mi * 16 + 4 * g + r) * DH + wv * 64 + f * 16 + ln] =
            (bf16_t)(acc[mi][f][r] * inv[mi][r]);
}

// ---------------------------------------------------------------------------
// kmatA: A = o_rgb @ atte_w.  grid (16, 4, 16), block 256.
// A tile staged once (XOR-swizzled, b128 kappa' frags); W frags from global.
// ---------------------------------------------------------------------------
__global__ __launch_bounds__(256, 4)
void kmatA(const bf16_t* __restrict__ o_rgb, const bf16_t* __restrict__ Wa,
           bf16_t* __restrict__ Aout) {
  const int t0 = blockIdx.x * 64;
  const int h  = blockIdx.y;
  const int nn = blockIdx.z;
  const bf16_t* O = o_rgb + (size_t)(nn * NH + h) * Tdim * DH;
  bf16_t* Ao = Aout + (size_t)(nn * NH + h) * Tdim * DH;

  __shared__ __align__(128) bf16_t Alds[64 * 256];  // 32KB swizzled rows

  const int tid = threadIdx.x;
  const int lane = tid & 63, wv = tid >> 6;
  const int g = lane >> 4, ln = lane & 15;

  {  // stage 32KB contiguous -> swizzled
    const char* src = (const char*)(O + (size_t)t0 * DH);
#pragma unroll
    for (int j = 0; j < 8; ++j) {
      int gc = tid + j * 256;
      int row = gc >> 5;
      *(bf16x8*)((char*)Alds + ((gc * 16) ^ ((row & 7) << 4))) =
          *(const bf16x8*)(src + gc * 16);
    }
  }
  __syncthreads();

  f32x4 acc[4][4] = {};
  for (int kb = 0; kb < 8; ++kb) {
    bf16x8 af[4];
#pragma unroll
    for (int mi = 0; mi < 4; ++mi) {
      int row = mi * 16 + ln;
      af[mi] = *(const bf16x8*)((const char*)Alds +
               ((row * 512 + kb * 64 + g * 16) ^ ((row & 7) << 4)));
    }
    bf16x8 wf[4];
    const bf16_t* wt = Wa + (size_t)(h * 8 + kb) * 8192 + (wv * 4) * 512 + lane * 8;
#pragma unroll
    for (int f = 0; f < 4; ++f) wf[f] = *(const bf16x8*)(wt + f * 512);
#pragma unroll
    for (int mi = 0; mi < 4; ++mi)
#pragma unroll
      for (int f = 0; f < 4; ++f) acc[mi][f] = mm16(af[mi], wf[f], acc[mi][f]);
  }
#pragma unroll
  for (int mi = 0; mi < 4; ++mi)
#pragma unroll
    for (int f = 0; f < 4; ++f)
#pragma unroll
      for (int r = 0; r < 4; ++r)
        Ao[(size_t)(t0 + mi * 16 + 4 * g + r) * DH + wv * 64 + f * 16 + ln] =
            (bf16_t)acc[mi][f][r];
}

// ---------------------------------------------------------------------------
// kflash: both flash passes + epilogue.  grid 1024, block 256 (4 waves).
// bid -> p = (bid&7)*16 + (bid>>6), qx = (bid>>3)&7; 128 q-rows per block
// (32/wave, 2 row-groups).  s-tile = 32.
// K frags direct from global/L2 inside QK^T (issued+consumed BEFORE the
// V-DMA is issued, sched_barrier-pinned, so kf waits never drain the V
// prefetch).  V double-buffered in LDS via global_load_lds + tr-read.
// Swapped QK^T keeps P in registers.  No-max softmax: P = exp(S-8).
// ---------------------------------------------------------------------------
__global__ __launch_bounds__(256, 2)
void kflash(const bf16_t* __restrict__ o_rgb, const bf16_t* __restrict__ o_flow,
            const bf16_t* __restrict__ Aw,
            const float* __restrict__ rgb, const float* __restrict__ flow,
            float* __restrict__ out) {
  const int bid = blockIdx.x;
  const int p  = (bid & 7) * 16 + (bid >> 6);   // bijective, XCD-chunked
  const int qx = (bid >> 3) & 7;
  const int nn = p >> 3, h = (p >> 1) & 3, pass = p & 1;
  const int t0 = qx * 128;
  const size_t nhoff = (size_t)(nn * NH + h) * Tdim * DH;
  const bf16_t* Qp = (pass ? o_flow : Aw) + nhoff;
  const bf16_t* Kp = (pass ? Aw : o_flow) + nhoff;
  const bf16_t* Vp = (pass ? o_flow : o_rgb) + nhoff;
  const float*  Xr = (pass ? flow : rgb) + (size_t)nn * Ddim * Tdim;
  float* Op = out + (size_t)pass * NB * Ddim * Tdim + (size_t)nn * Ddim * Tdim;

  __shared__ __align__(128) bf16_t Vch[2][32 * 256];  // 2x16KB, [ech][k(32)][16]

  const int tid = threadIdx.x;
  const int lane = tid & 63, wv = tid >> 6;            // wv 0..3
  const int g = lane >> 4, ln = lane & 15;

  // Q fragments (kappa': contiguous 16B), rows t0 + wv*32 + rg*16 + ln.
  // Used as the B operand of the swapped QK^T (B col = lane&15 = q-row).
  bf16x8 qf[2][8];
#pragma unroll
  for (int rg = 0; rg < 2; ++rg) {
    const bf16_t* qrow = Qp + (size_t)(t0 + wv * 32 + rg * 16 + ln) * DH;
#pragma unroll
    for (int ks = 0; ks < 8; ++ks)
      qf[rg][ks] = *(const bf16x8*)(qrow + ks * 32 + 8 * g);
  }

  // async stage of one 32-row V tile into buffer b (4 chunks per thread).
  // V: chunked source (row stride 512B, 16B chunks), linear dest
  // [ech(16)][k(32)][16].  LDS dest: wave-uniform base + lane*16.
  auto stage = [&](int b, int s0) {
    const char* Vs = (const char*)Vp + (size_t)s0 * 512;
    char* Vd = (char*)&Vch[b][0] + wv * 1024;
#pragma unroll
    for (int j = 0; j < 4; ++j) {
      int gc = j * 256 + tid;                    // 16B chunk index, 0..1023
      int ech = gc >> 6, kk = (gc & 63) >> 1, half = gc & 1;
      gload16(Vs + kk * 512 + (ech * 2 + half) * 16, Vd + j * 4096);
    }
  };

  f32x4 eacc[2][16] = {};
  float l_par[2] = {0.f, 0.f};

  stage(0, 0);
  __syncthreads();           // vmcnt(0) drain + barrier: tile 0 visible

  int cur = 0;
  for (int s0 = 0; s0 < Tdim; s0 += 32) {
    // S^T = K Q^T (swapped): K frags DIRECT from global/L2 as the A operand
    // (A row = lane&15 = s-row within nf block, k = ks*32 + 8g + i).
    // Result: lane holds q-row = rg*16 + ln, s = nf*16 + 4g + r.
    // All kf loads issue + are awaited here, with NO DMA outstanding ->
    // counted vmcnt waits never touch the V prefetch.
    f32x4 sacc[2][2] = {};
    const bf16_t* kr0 = Kp + (size_t)(s0 + ln) * DH + 8 * g;
    const bf16_t* kr1 = kr0 + 16 * DH;
#pragma unroll
    for (int ks = 0; ks < 8; ++ks) {
      bf16x8 kf0 = *(const bf16x8*)(kr0 + ks * 32);
      bf16x8 kf1 = *(const bf16x8*)(kr1 + ks * 32);
      sacc[0][0] = mm16(kf0, qf[0][ks], sacc[0][0]);
      sacc[1][0] = mm16(kf0, qf[1][ks], sacc[1][0]);
      sacc[0][1] = mm16(kf1, qf[0][ks], sacc[0][1]);
      sacc[1][1] = mm16(kf1, qf[1][ks], sacc[1][1]);
    }

    // Pin: QK^T (incl. all kf loads) strictly before the V-DMA issue, and
    // the DMA issue strictly before softmax/PV (which hide its latency).
    __builtin_amdgcn_sched_barrier(0);
    if (s0 + 32 < Tdim) stage(cur ^ 1, s0 + 32);
    __builtin_amdgcn_sched_barrier(0);

    // P = exp(S - 8) fully in-register.  Slot set per lane:
    // lo j: s = 4g+j (nf=0, r=j), hi j: s = 16+4g+j (nf=1) == kappa_tr A-frag.
    bf16x8 pa[2];
#pragma unroll
    for (int rg = 0; rg < 2; ++rg) {
      bf16x4 lo, hi;
#pragma unroll
      for (int r = 0; r < 4; ++r) {
        float p0 = __expf(sacc[rg][0][r] - 8.0f);
        float p1 = __expf(sacc[rg][1][r] - 8.0f);
        l_par[rg] += p0 + p1;
        lo[r] = (bf16_t)p0;
        hi[r] = (bf16_t)p1;
      }
      pa[rg] = cmb(lo, hi);
    }

    // E += P @ V  (P in registers; V via tr-read, shared by both rg)
#pragma unroll
    for (int nb4 = 0; nb4 < 4; ++nb4) {
      bf16x4 vlo[4], vhi[4];
#pragma unroll
      for (int j = 0; j < 4; ++j)
        tr_pair(&Vch[cur][(nb4 * 4 + j) * 512], lane, vlo[j], vhi[j]);
      lgkm0_fence();
#pragma unroll
      for (int j = 0; j < 4; ++j) {
        bf16x8 vf = cmb(vlo[j], vhi[j]);
        eacc[0][nb4 * 4 + j] = mm16(pa[0], vf, eacc[0][nb4 * 4 + j]);
        eacc[1][nb4 * 4 + j] = mm16(pa[1], vf, eacc[1][nb4 * 4 + j]);
      }
    }

    __syncthreads();         // drains V-DMA (tile i+1) + all lgkm
    cur ^= 1;
  }

  // epilogue: reduce l (lanes ln,16+ln,32+ln,48+ln cover all 32 s), fetch
  // per-output-row invl via width-16 shfl, gelu, residual, tanh.
  float invl[2][4];
#pragma unroll
  for (int rg = 0; rg < 2; ++rg) {
    float l = l_par[rg];
    l += __shfl_xor(l, 16); l += __shfl_xor(l, 32);
    // every lane now holds the total for q-row rg*16 + ln
#pragma unroll
    for (int r = 0; r < 4; ++r)
      invl[rg][r] = 1.0f / __shfl(l, 4 * g + r, 16);
  }
#pragma unroll
  for (int rg = 0; rg < 2; ++rg)
#pragma unroll
    for (int nb = 0; nb < 16; ++nb)
#pragma unroll
      for (int r = 0; r < 4; ++r) {
        float e = eacc[rg][nb][r] * invl[rg][r];
        float ge = 0.5f * e * (1.0f + erff(e * 0.70710678118f));
        int trow = t0 + wv * 32 + rg * 16 + 4 * g + r;
        int col = h * 256 + nb * 16 + ln;
        size_t idx = (size_t)trow * Tdim + col;
        Op[idx] = tanhf(ge + Xr[idx]);
      }
}

// ---------------------------------------------------------------------------
extern "C" void kernel_launch(void* const* d_in, const int* in_sizes, int n_in,
                              void* d_out, int out_size, void* d_ws, size_t ws_size,
                              hipStream_t stream) {
  const float* rgb   = (const float*)d_in[0];
  const float* flow  = (const float*)d_in[1];
  const float* rgbp  = (const float*)d_in[2];
  const float* flowp = (const float*)d_in[3];
  const float* attw  = (const float*)d_in[4];
  float* out = (float*)d_out;

  const size_t OSZ = (size_t)NB * NH * Tdim * DH;   // 16.7M bf16
  bf16_t* o_rgb  = (bf16_t*)d_ws;                   // 32 MB
  bf16_t* o_flow = o_rgb + OSZ;                     // 32 MB
  bf16_t* Aw     = o_flow + OSZ;                    // 32 MB
  bf16_t* Wl     = Aw + OSZ;                        // 4 MB (2M elems)
  bf16_t* Wa     = Wl + (size_t)2 * NH * 32 * 8192; // 0.5 MB

  kconvP<<<1024, 256, 0, stream>>>(rgbp, flowp, Wl);
  kconvA<<<128, 256, 0, stream>>>(attw, Wa);
  kproj<<<dim3(16, 4, 32), 256, 0, stream>>>(rgb, flow, Wl, o_rgb, o_flow);
  kmatA<<<dim3(16, 4, 16), 256, 0, stream>>>(o_rgb, Wa, Aw);
  kflash<<<1024, 256, 0, stream>>>(o_rgb, o_flow, Aw, rgb, flow, out);
}

// Round 10
// 344.974 us; speedup vs baseline: 1.5763x; 1.5763x over previous
//
#include <hip/hip_runtime.h>
#include <hip/hip_bf16.h>
#include <cstdint>
#include <cstddef>

// ---------------------------------------------------------------------------
// MCA bilinear-attention fusion on MI355X (gfx950), bf16 MFMA pipeline.
//   kconvW: rgb_proj/flow_proj/atte_w f32 -> bf16 MFMA-fragment order (ws)
//   kproj : o = l2norm(X^T @ proj) -> ws; FUSED (mod==0): A = o_rgb@atte_w
//   kflash: two flash passes (row/col softmax of att), no-max softmax,
//           fused fast gelu + residual + tanh epilogue -> d_out (f32)
//
// R7 (champion): 4 waves/block, 32 q-rows/wave (rg=2 sharing), K+V LDS-staged
//     async, swapped QK^T + in-register P: 306us kflash / 415 total.
// R8 (occupancy-for-sharing trade) and R6/R9 (K direct from L2, both orders)
//     all regressed -> K stays LDS-staged; R7 geometry is wedged at the
//     256-reg/wave boundary (124 VGPR + 128 AGPR) so no extra pipelining regs.
// R10: register-neutral basket outside the kflash sync structure:
//   (1) kflash epilogue fast-math: tanh-form GELU + exp-based tanh
//       (1-2*rcp(e^2x+1), NaN-safe) replaces erff/tanhf libm (~50->~15 instr
//       per output, 128 outputs/thread).
//   (2) kmatA FUSED into kproj (same 64-row tile): normalized acc -> swizzled
//       Alds -> kmatA's GEMM -> Aw.  o_rgb round-trip + 1 launch deleted.
//   (3) kconvP+kconvA merged into kconvW (1 launch).
// ---------------------------------------------------------------------------

typedef __bf16 bf16_t;
typedef bf16_t bf16x4 __attribute__((ext_vector_type(4)));
typedef bf16_t bf16x8 __attribute__((ext_vector_type(8)));
typedef float  f32x4  __attribute__((ext_vector_type(4)));

#define DEV static __device__ __forceinline__

constexpr int Tdim = 1024;   // t
constexpr int Ddim = 1024;   // d
constexpr int DH   = 256;    // d/h
constexpr int NH   = 4;      // heads
constexpr int NB   = 16;     // batch n

DEV f32x4 mm16(bf16x8 a, bf16x8 b, f32x4 c) {
  return __builtin_amdgcn_mfma_f32_16x16x32_bf16(a, b, c, 0, 0, 0);
}

DEV bf16x8 cmb(bf16x4 lo, bf16x4 hi) {
  return __builtin_shufflevector(lo, hi, 0, 1, 2, 3, 4, 5, 6, 7);
}

// Hardware transpose read from a [K][16] bf16 chunk: lane l gets k = 4g+j (lo)
// and k = 16+4g+j (hi, offset:512B) of column (l&15).  kappa_tr(g,i).
DEV void tr_pair(const bf16_t* base, int lane, bf16x4& lo, bf16x4& hi) {
  uint32_t a = (uint32_t)(uintptr_t)base + (uint32_t)(lane * 8);
  asm volatile("ds_read_b64_tr_b16 %0, %2\n\t"
               "ds_read_b64_tr_b16 %1, %2 offset:512"
               : "=v"(lo), "=v"(hi)
               : "v"(a));
}

DEV void lgkm0_fence() {
  asm volatile("s_waitcnt lgkmcnt(0)" ::: "memory");
  __builtin_amdgcn_sched_barrier(0);
}

// async global -> LDS, 16B per lane; lds dest must be wave-uniform base.
DEV void gload16(const void* g, void* l) {
  __builtin_amdgcn_global_load_lds(
      (const __attribute__((address_space(1))) uint32_t*)g,
      (__attribute__((address_space(3))) uint32_t*)l, 16, 0, 0);
}

// fast tanh: 1 - 2/(e^{2x}+1).  Saturates correctly (a->0 => -1, a->inf => 1),
// no NaN (a+1 > 0).  ~5 instr vs ~25 for libm tanhf.
DEV float ftanh(float x) {
  float a = __expf(2.0f * x);
  return 1.0f - 2.0f * __builtin_amdgcn_rcpf(a + 1.0f);
}

// ---------------------------------------------------------------------------
// kconvW: merged weight converters.
// blocks 0..1023: rgb_proj/flow_proj -> Wl (kappa_tr order)
//   Wl[mod][h][kb(32)][nf(16)][g(4)][c(16)][i(8)], k = kb*32 + tr(g,i).
// blocks 1024..1151: atte_w -> Wa (kappa' order)
//   Wa[h][kb(8)][nf(16)][g(4)][c(16)][i(8)], k = kb*32 + 8g + i.
// ---------------------------------------------------------------------------
__global__ void kconvW(const float* __restrict__ rgbp,
                       const float* __restrict__ flowp,
                       const float* __restrict__ attw,
                       bf16_t* __restrict__ Wl, bf16_t* __restrict__ Wa) {
  int bid = blockIdx.x;
  if (bid < 1024) {
    int oc = bid * 256 + threadIdx.x;               // 0..262143
    int c = oc & 15, g = (oc >> 4) & 3, nf = (oc >> 6) & 15;
    int kb = (oc >> 10) & 31, h = (oc >> 15) & 3, mod = oc >> 17;
    const float* src = (mod ? flowp : rgbp) + (size_t)h * Ddim * DH + nf * 16 + c;
    bf16x8 v;
#pragma unroll
    for (int i = 0; i < 8; ++i) {
      int k = kb * 32 + ((i < 4) ? 4 * g + i : 12 + 4 * g + i);
      v[i] = (bf16_t)src[(size_t)k * DH];
    }
    *(bf16x8*)(Wl + (size_t)oc * 8) = v;
  } else {
    int oc = (bid - 1024) * 256 + threadIdx.x;      // 0..32767
    int c = oc & 15, g = (oc >> 4) & 3, nf = (oc >> 6) & 15;
    int kb = (oc >> 10) & 7, h = oc >> 13;
    const float* src = attw + (size_t)h * DH * DH + nf * 16 + c;
    bf16x8 v;
#pragma unroll
    for (int i = 0; i < 8; ++i) {
      int k = kb * 32 + 8 * g + i;
      v[i] = (bf16_t)src[(size_t)k * DH];
    }
    *(bf16x8*)(Wa + (size_t)oc * 8) = v;
  }
}

// ---------------------------------------------------------------------------
// kproj: o = l2norm(X^T @ proj).  grid (16, 4, 32) z = nn*2+mod, block 256.
// A (X^T tile) via chunked LDS + tr-read; W fragments direct from global.
// FUSED (mod==0): this block's 64 normalized rows -> swizzled Alds ->
// kmatA's GEMM (A = o_rgb @ atte_w) -> Aw.  Same 64-row tiling as old kmatA.
// ---------------------------------------------------------------------------
__global__ __launch_bounds__(256, 4)
void kproj(const float* __restrict__ rgb, const float* __restrict__ flow,
           const bf16_t* __restrict__ Wl, const bf16_t* __restrict__ Wa,
           bf16_t* __restrict__ o_rgb, bf16_t* __restrict__ o_flow,
           bf16_t* __restrict__ Aout) {
  const int t0  = blockIdx.x * 64;
  const int h   = blockIdx.y;
  const int nn  = blockIdx.z >> 1;
  const int mod = blockIdx.z & 1;
  const float* X = (mod ? flow : rgb) + (size_t)nn * Ddim * Tdim + t0;
  const bf16_t* Wb = Wl + (size_t)(mod * NH + h) * 32 * 8192;
  bf16_t* O = (mod ? o_flow : o_rgb) + (size_t)(nn * NH + h) * Tdim * DH;

  __shared__ __align__(128) bf16_t Ach[4 * 512];   // [tchunk][k=32][16]
  __shared__ float sq[4][64];
  __shared__ __align__(128) bf16_t Alds[64 * 256]; // 32KB swizzled (fused GEMM)

  const int tid = threadIdx.x;
  const int lane = tid & 63, wv = tid >> 6;
  const int g = lane >> 4, ln = lane & 15;

  f32x4 acc[4][4] = {};   // [mi][f]: rows t0+mi*16+4g+r, cols wv*64+f*16+ln
  const int akk = tid >> 3, atoff = (tid & 7) * 8;

  for (int kb = 0; kb < 32; ++kb) {
    {  // stage A tile (column-major in X), convert to bf16, chunked
      const float* srcx = X + (size_t)(kb * 32 + akk) * Tdim + atoff;
      float4 f0 = *(const float4*)srcx;
      float4 f1 = *(const float4*)(srcx + 4);
      bf16x8 v = {(bf16_t)f0.x, (bf16_t)f0.y, (bf16_t)f0.z, (bf16_t)f0.w,
                  (bf16_t)f1.x, (bf16_t)f1.y, (bf16_t)f1.z, (bf16_t)f1.w};
      *(bf16x8*)&Ach[(atoff >> 4) * 512 + akk * 16 + (atoff & 15)] = v;
    }
    __syncthreads();

    bf16x4 alo[4], ahi[4];
#pragma unroll
    for (int mi = 0; mi < 4; ++mi) tr_pair(&Ach[mi * 512], lane, alo[mi], ahi[mi]);
    bf16x8 wf[4];
    const bf16_t* wt = Wb + (size_t)kb * 8192 + (wv * 4) * 512 + lane * 8;
#pragma unroll
    for (int f = 0; f < 4; ++f) wf[f] = *(const bf16x8*)(wt + f * 512);
    lgkm0_fence();
#pragma unroll
    for (int mi = 0; mi < 4; ++mi) {
      bf16x8 a = cmb(alo[mi], ahi[mi]);
#pragma unroll
      for (int f = 0; f < 4; ++f) acc[mi][f] = mm16(a, wf[f], acc[mi][f]);
    }
    __syncthreads();
  }

  // row L2 norms
  float inv[4][4];
#pragma unroll
  for (int mi = 0; mi < 4; ++mi)
#pragma unroll
    for (int r = 0; r < 4; ++r) {
      float s = 0.f;
#pragma unroll
      for (int f = 0; f < 4; ++f) { float v = acc[mi][f][r]; s += v * v; }
      s += __shfl_xor(s, 1); s += __shfl_xor(s, 2);
      s += __shfl_xor(s, 4); s += __shfl_xor(s, 8);
      if (ln == 0) sq[wv][mi * 16 + 4 * g + r] = s;
    }
  __syncthreads();
#pragma unroll
  for (int mi = 0; mi < 4; ++mi)
#pragma unroll
    for (int r = 0; r < 4; ++r) {
      int rl = mi * 16 + 4 * g + r;
      float s = sq[0][rl] + sq[1][rl] + sq[2][rl] + sq[3][rl];
      inv[mi][r] = 1.0f / fmaxf(sqrtf(s), 1e-12f);
    }

  // write O (global) and, for mod==0, the same values into swizzled Alds
#pragma unroll
  for (int mi = 0; mi < 4; ++mi)
#pragma unroll
    for (int f = 0; f < 4; ++f)
#pragma unroll
      for (int r = 0; r < 4; ++r) {
        bf16_t val = (bf16_t)(acc[mi][f][r] * inv[mi][r]);
        int row = mi * 16 + 4 * g + r;
        int col = wv * 64 + f * 16 + ln;
        O[(size_t)(t0 + row) * DH + col] = val;
        if (mod == 0)
          *(bf16_t*)((char*)Alds + ((row * 512 + col * 2) ^ ((row & 7) << 4))) = val;
      }

  if (mod != 0) return;

  // ---- fused kmatA: A = o_rgb(this tile) @ atte_w -> Aout ----
  __syncthreads();
  bf16_t* Ao = Aout + (size_t)(nn * NH + h) * Tdim * DH;
  f32x4 acc2[4][4] = {};
  for (int kb = 0; kb < 8; ++kb) {
    bf16x8 af[4];
#pragma unroll
    for (int mi = 0; mi < 4; ++mi) {
      int row = mi * 16 + ln;
      af[mi] = *(const bf16x8*)((const char*)Alds +
               ((row * 512 + kb * 64 + g * 16) ^ ((row & 7) << 4)));
    }
    bf16x8 wf[4];
    const bf16_t* wt = Wa + (size_t)(h * 8 + kb) * 8192 + (wv * 4) * 512 + lane * 8;
#pragma unroll
    for (int f = 0; f < 4; ++f) wf[f] = *(const bf16x8*)(wt + f * 512);
#pragma unroll
    for (int mi = 0; mi < 4; ++mi)
#pragma unroll
      for (int f = 0; f < 4; ++f) acc2[mi][f] = mm16(af[mi], wf[f], acc2[mi][f]);
  }
#pragma unroll
  for (int mi = 0; mi < 4; ++mi)
#pragma unroll
    for (int f = 0; f < 4; ++f)
#pragma unroll
      for (int r = 0; r < 4; ++r)
        Ao[(size_t)(t0 + mi * 16 + 4 * g + r) * DH + wv * 64 + f * 16 + ln] =
            (bf16_t)acc2[mi][f][r];
}

// ---------------------------------------------------------------------------
// kflash: both flash passes + epilogue.  grid 1024, block 256 (4 waves).
// bid -> p = (bid&7)*16 + (bid>>6), qx = (bid>>3)&7; 128 q-rows per block
// (32/wave, 2 row-groups).  s-tile = 32.
// K+V double-buffered in LDS via global_load_lds (no VMEM in compute ->
// vmcnt drains only at the tile barrier; true prefetch).  Swapped QK^T
// (mm16(K,Q)) keeps P in registers: lane q-row = rg*16+ln, s = nf*16+4g+r
// == kappa_tr A-frag slots for PV.  No-max softmax: P = exp(S-8).
// Epilogue: fast tanh-form GELU + fast tanh (R10).
// ---------------------------------------------------------------------------
__global__ __launch_bounds__(256, 2)
void kflash(const bf16_t* __restrict__ o_rgb, const bf16_t* __restrict__ o_flow,
            const bf16_t* __restrict__ Aw,
            const float* __restrict__ rgb, const float* __restrict__ flow,
            float* __restrict__ out) {
  const int bid = blockIdx.x;
  const int p  = (bid & 7) * 16 + (bid >> 6);   // bijective, XCD-chunked
  const int qx = (bid >> 3) & 7;
  const int nn = p >> 3, h = (p >> 1) & 3, pass = p & 1;
  const int t0 = qx * 128;
  const size_t nhoff = (size_t)(nn * NH + h) * Tdim * DH;
  const bf16_t* Qp = (pass ? o_flow : Aw) + nhoff;
  const bf16_t* Kp = (pass ? Aw : o_flow) + nhoff;
  const bf16_t* Vp = (pass ? o_flow : o_rgb) + nhoff;
  const float*  Xr = (pass ? flow : rgb) + (size_t)nn * Ddim * Tdim;
  float* Op = out + (size_t)pass * NB * Ddim * Tdim + (size_t)nn * Ddim * Tdim;

  __shared__ __align__(128) bf16_t Klds[2][32 * 256];  // 2x16KB, XOR-swizzled
  __shared__ __align__(128) bf16_t Vch [2][32 * 256];  // 2x16KB, [ech][k(32)][16]

  const int tid = threadIdx.x;
  const int lane = tid & 63, wv = tid >> 6;            // wv 0..3
  const int g = lane >> 4, ln = lane & 15;

  // Q fragments (kappa': contiguous 16B), rows t0 + wv*32 + rg*16 + ln.
  // Used as the B operand of the swapped QK^T (B col = lane&15 = q-row).
  bf16x8 qf[2][8];
#pragma unroll
  for (int rg = 0; rg < 2; ++rg) {
    const bf16_t* qrow = Qp + (size_t)(t0 + wv * 32 + rg * 16 + ln) * DH;
#pragma unroll
    for (int ks = 0; ks < 8; ++ks)
      qf[rg][ks] = *(const bf16x8*)(qrow + ks * 32 + 8 * g);
  }

  // async stage of one 32-row K/V tile into buffer b (8 chunks per thread).
  // K: linear LDS dest, pre-swizzled global source (involutive XOR of byte
  //    bits 4-6 with row bits 9-11).  V: chunked source (row stride 512B,
  //    16B chunks), linear dest.  LDS dest: wave-uniform base + lane*16.
  auto stage = [&](int b, int s0) {
    const char* Ks = (const char*)Kp + (size_t)s0 * 512;
    const char* Vs = (const char*)Vp + (size_t)s0 * 512;
    char* Kd = (char*)&Klds[b][0] + wv * 1024;
    char* Vd = (char*)&Vch[b][0] + wv * 1024;
#pragma unroll
    for (int j = 0; j < 4; ++j) {
      int gc = j * 256 + tid;                    // 16B chunk index, 0..1023
      int d  = gc * 16;
      gload16(Ks + (d ^ (((d >> 9) & 7) << 4)), Kd + j * 4096);
      int ech = gc >> 6, kk = (gc & 63) >> 1, half = gc & 1;
      gload16(Vs + kk * 512 + (ech * 2 + half) * 16, Vd + j * 4096);
    }
  };

  f32x4 eacc[2][16] = {};
  float l_par[2] = {0.f, 0.f};

  stage(0, 0);
  __syncthreads();           // vmcnt(0) drain + barrier: tile 0 visible

  int cur = 0;
  for (int s0 = 0; s0 < Tdim; s0 += 32) {
    if (s0 + 32 < Tdim) stage(cur ^ 1, s0 + 32);   // async, flies under compute

    // S^T = K Q^T (swapped): K frags from LDS as the A operand
    // (A row = lane&15 = s-row within nf block, k = ks*32 + 8g + i).
    // Result: lane holds q-row = rg*16 + ln, s = nf*16 + 4g + r.
    f32x4 sacc[2][2] = {};
#pragma unroll
    for (int ks = 0; ks < 8; ++ks) {
      int row0 = ln, row1 = 16 + ln;
      bf16x8 kf0 = *(const bf16x8*)((const char*)&Klds[cur][0] +
          ((row0 * 512 + ks * 64 + g * 16) ^ ((row0 & 7) << 4)));
      bf16x8 kf1 = *(const bf16x8*)((const char*)&Klds[cur][0] +
          ((row1 * 512 + ks * 64 + g * 16) ^ ((row1 & 7) << 4)));
      sacc[0][0] = mm16(kf0, qf[0][ks], sacc[0][0]);
      sacc[1][0] = mm16(kf0, qf[1][ks], sacc[1][0]);
      sacc[0][1] = mm16(kf1, qf[0][ks], sacc[0][1]);
      sacc[1][1] = mm16(kf1, qf[1][ks], sacc[1][1]);
    }

    // P = exp(S - 8) fully in-register.  Slot set per lane:
    // lo j: s = 4g+j (nf=0, r=j), hi j: s = 16+4g+j (nf=1) == kappa_tr A-frag.
    bf16x8 pa[2];
#pragma unroll
    for (int rg = 0; rg < 2; ++rg) {
      bf16x4 lo, hi;
#pragma unroll
      for (int r = 0; r < 4; ++r) {
        float p0 = __expf(sacc[rg][0][r] - 8.0f);
        float p1 = __expf(sacc[rg][1][r] - 8.0f);
        l_par[rg] += p0 + p1;
        lo[r] = (bf16_t)p0;
        hi[r] = (bf16_t)p1;
      }
      pa[rg] = cmb(lo, hi);
    }

    // E += P @ V  (P in registers; V via tr-read, shared by both rg)
#pragma unroll
    for (int nb4 = 0; nb4 < 4; ++nb4) {
      bf16x4 vlo[4], vhi[4];
#pragma unroll
      for (int j = 0; j < 4; ++j)
        tr_pair(&Vch[cur][(nb4 * 4 + j) * 512], lane, vlo[j], vhi[j]);
      lgkm0_fence();
#pragma unroll
      for (int j = 0; j < 4; ++j) {
        bf16x8 vf = cmb(vlo[j], vhi[j]);
        eacc[0][nb4 * 4 + j] = mm16(pa[0], vf, eacc[0][nb4 * 4 + j]);
        eacc[1][nb4 * 4 + j] = mm16(pa[1], vf, eacc[1][nb4 * 4 + j]);
      }
    }

    __syncthreads();         // next tile landed; all waves done with cur
    cur ^= 1;
  }

  // epilogue: reduce l (lanes ln,16+ln,32+ln,48+ln cover all 32 s), fetch
  // per-output-row invl via width-16 shfl, fast gelu, residual, fast tanh.
  float invl[2][4];
#pragma unroll
  for (int rg = 0; rg < 2; ++rg) {
    float l = l_par[rg];
    l += __shfl_xor(l, 16); l += __shfl_xor(l, 32);
    // every lane now holds the total for q-row rg*16 + ln
#pragma unroll
    for (int r = 0; r < 4; ++r)
      invl[rg][r] = 1.0f / __shfl(l, 4 * g + r, 16);
  }
#pragma unroll
  for (int rg = 0; rg < 2; ++rg)
#pragma unroll
    for (int nb = 0; nb < 16; ++nb)
#pragma unroll
      for (int r = 0; r < 4; ++r) {
        float e = eacc[rg][nb][r] * invl[rg][r];
        // tanh-form GELU (|e| small -> approx error < 2e-4)
        float u = 0.79788456f * (e + 0.044715f * e * e * e);
        float ge = 0.5f * e * (1.0f + ftanh(u));
        int trow = t0 + wv * 32 + rg * 16 + 4 * g + r;
        int col = h * 256 + nb * 16 + ln;
        size_t idx = (size_t)trow * Tdim + col;
        Op[idx] = ftanh(ge + Xr[idx]);
      }
}

// ---------------------------------------------------------------------------
extern "C" void kernel_launch(void* const* d_in, const int* in_sizes, int n_in,
                              void* d_out, int out_size, void* d_ws, size_t ws_size,
                              hipStream_t stream) {
  const float* rgb   = (const float*)d_in[0];
  const float* flow  = (const float*)d_in[1];
  const float* rgbp  = (const float*)d_in[2];
  const float* flowp = (const float*)d_in[3];
  const float* attw  = (const float*)d_in[4];
  float* out = (float*)d_out;

  const size_t OSZ = (size_t)NB * NH * Tdim * DH;   // 16.7M bf16
  bf16_t* o_rgb  = (bf16_t*)d_ws;                   // 32 MB
  bf16_t* o_flow = o_rgb + OSZ;                     // 32 MB
  bf16_t* Aw     = o_flow + OSZ;                    // 32 MB
  bf16_t* Wl     = Aw + OSZ;                        // 4 MB (2M elems)
  bf16_t* Wa     = Wl + (size_t)2 * NH * 32 * 8192; // 0.5 MB

  kconvW<<<1152, 256, 0, stream>>>(rgbp, flowp, attw, Wl, Wa);
  kproj<<<dim3(16, 4, 32), 256, 0, stream>>>(rgb, flow, Wl, Wa,
                                             o_rgb, o_flow, Aw);
  kflash<<<1024, 256, 0, stream>>>(o_rgb, o_flow, Aw, rgb, flow, out);
}

// Round 11
// 315.159 us; speedup vs baseline: 1.7254x; 1.0946x over previous
//
#include <hip/hip_runtime.h>
#include <hip/hip_bf16.h>
#include <cstdint>
#include <cstddef>

// ---------------------------------------------------------------------------
// MCA bilinear-attention fusion on MI355X (gfx950), bf16 MFMA pipeline.
//   kconvW: rgb_proj/flow_proj/atte_w f32 -> bf16 MFMA-fragment order (ws)
//   kproj : o = l2norm(X^T @ proj) -> ws; FUSED (mod==0): A = o_rgb@atte_w
//   kflash: two flash passes (row/col softmax of att), no-max softmax,
//           fused fast gelu + residual + tanh epilogue -> d_out (f32)
//
// R7/R10 (champion kflash): 4 waves/block, 32 q-rows/wave (rg=2 sharing),
//     K+V LDS-staged async, swapped QK^T + in-register P, fast-math epilogue:
//     206us kflash.  Register-wedged at 256 regs/wave -> structure final.
// R11: pipeline kproj (the last serial kernel; was stage->bar->compute->bar):
//   (1) W fragments via global_load_lds double-buffer (L2 latency prefetched
//       one kb ahead; zero staging VGPRs).  W LDS read is contiguous b128.
//   (2) Ach (X chunk) double-buffered -> ONE barrier per kb; a wave's stage
//       of kb+1 overlaps other waves' compute of kb.
//   (3) Both dbufs alias the first 24KB of Alds (dead until the fused GEMM)
//       -> LDS 37->33KB, still 4 blocks/CU.
//   (4) W-DMA issued before the X f32 loads (sched_barrier-pinned) so the
//       X wait is a counted vmcnt that leaves the DMA in flight (R6/R9 rule).
//   kflash byte-identical to R10.
// ---------------------------------------------------------------------------

typedef __bf16 bf16_t;
typedef bf16_t bf16x4 __attribute__((ext_vector_type(4)));
typedef bf16_t bf16x8 __attribute__((ext_vector_type(8)));
typedef float  f32x4  __attribute__((ext_vector_type(4)));

#define DEV static __device__ __forceinline__

constexpr int Tdim = 1024;   // t
constexpr int Ddim = 1024;   // d
constexpr int DH   = 256;    // d/h
constexpr int NH   = 4;      // heads
constexpr int NB   = 16;     // batch n

DEV f32x4 mm16(bf16x8 a, bf16x8 b, f32x4 c) {
  return __builtin_amdgcn_mfma_f32_16x16x32_bf16(a, b, c, 0, 0, 0);
}

DEV bf16x8 cmb(bf16x4 lo, bf16x4 hi) {
  return __builtin_shufflevector(lo, hi, 0, 1, 2, 3, 4, 5, 6, 7);
}

// Hardware transpose read from a [K][16] bf16 chunk: lane l gets k = 4g+j (lo)
// and k = 16+4g+j (hi, offset:512B) of column (l&15).  kappa_tr(g,i).
DEV void tr_pair(const bf16_t* base, int lane, bf16x4& lo, bf16x4& hi) {
  uint32_t a = (uint32_t)(uintptr_t)base + (uint32_t)(lane * 8);
  asm volatile("ds_read_b64_tr_b16 %0, %2\n\t"
               "ds_read_b64_tr_b16 %1, %2 offset:512"
               : "=v"(lo), "=v"(hi)
               : "v"(a));
}

DEV void lgkm0_fence() {
  asm volatile("s_waitcnt lgkmcnt(0)" ::: "memory");
  __builtin_amdgcn_sched_barrier(0);
}

// async global -> LDS, 16B per lane; lds dest must be wave-uniform base.
DEV void gload16(const void* g, void* l) {
  __builtin_amdgcn_global_load_lds(
      (const __attribute__((address_space(1))) uint32_t*)g,
      (__attribute__((address_space(3))) uint32_t*)l, 16, 0, 0);
}

// fast tanh: 1 - 2/(e^{2x}+1).  Saturates correctly (a->0 => -1, a->inf => 1),
// no NaN (a+1 > 0).  ~5 instr vs ~25 for libm tanhf.
DEV float ftanh(float x) {
  float a = __expf(2.0f * x);
  return 1.0f - 2.0f * __builtin_amdgcn_rcpf(a + 1.0f);
}

// ---------------------------------------------------------------------------
// kconvW: merged weight converters.
// blocks 0..1023: rgb_proj/flow_proj -> Wl (kappa_tr order)
//   Wl[mod][h][kb(32)][nf(16)][g(4)][c(16)][i(8)], k = kb*32 + tr(g,i).
// blocks 1024..1151: atte_w -> Wa (kappa' order)
//   Wa[h][kb(8)][nf(16)][g(4)][c(16)][i(8)], k = kb*32 + 8g + i.
// ---------------------------------------------------------------------------
__global__ void kconvW(const float* __restrict__ rgbp,
                       const float* __restrict__ flowp,
                       const float* __restrict__ attw,
                       bf16_t* __restrict__ Wl, bf16_t* __restrict__ Wa) {
  int bid = blockIdx.x;
  if (bid < 1024) {
    int oc = bid * 256 + threadIdx.x;               // 0..262143
    int c = oc & 15, g = (oc >> 4) & 3, nf = (oc >> 6) & 15;
    int kb = (oc >> 10) & 31, h = (oc >> 15) & 3, mod = oc >> 17;
    const float* src = (mod ? flowp : rgbp) + (size_t)h * Ddim * DH + nf * 16 + c;
    bf16x8 v;
#pragma unroll
    for (int i = 0; i < 8; ++i) {
      int k = kb * 32 + ((i < 4) ? 4 * g + i : 12 + 4 * g + i);
      v[i] = (bf16_t)src[(size_t)k * DH];
    }
    *(bf16x8*)(Wl + (size_t)oc * 8) = v;
  } else {
    int oc = (bid - 1024) * 256 + threadIdx.x;      // 0..32767
    int c = oc & 15, g = (oc >> 4) & 3, nf = (oc >> 6) & 15;
    int kb = (oc >> 10) & 7, h = oc >> 13;
    const float* src = attw + (size_t)h * DH * DH + nf * 16 + c;
    bf16x8 v;
#pragma unroll
    for (int i = 0; i < 8; ++i) {
      int k = kb * 32 + 8 * g + i;
      v[i] = (bf16_t)src[(size_t)k * DH];
    }
    *(bf16x8*)(Wa + (size_t)oc * 8) = v;
  }
}

// ---------------------------------------------------------------------------
// kproj: o = l2norm(X^T @ proj).  grid (16, 4, 32) z = nn*2+mod, block 256.
// R11 pipelined: per kb-step, ONE barrier; W tile DMA'd (global_load_lds)
// into a double buffer; X chunk staged (reg path, f32->bf16) into a second
// double buffer; both dbufs alias the first 24KB of Alds (dead until the
// fused GEMM).  Compute(kb) reads buffers filled at step kb-1.
// FUSED (mod==0): normalized rows -> swizzled Alds -> A = o_rgb@atte_w -> Aw.
// ---------------------------------------------------------------------------
__global__ __launch_bounds__(256, 4)
void kproj(const float* __restrict__ rgb, const float* __restrict__ flow,
           const bf16_t* __restrict__ Wl, const bf16_t* __restrict__ Wa,
           bf16_t* __restrict__ o_rgb, bf16_t* __restrict__ o_flow,
           bf16_t* __restrict__ Aout) {
  const int t0  = blockIdx.x * 64;
  const int h   = blockIdx.y;
  const int nn  = blockIdx.z >> 1;
  const int mod = blockIdx.z & 1;
  const float* X = (mod ? flow : rgb) + (size_t)nn * Ddim * Tdim + t0;
  const bf16_t* Wb = Wl + (size_t)(mod * NH + h) * 32 * 8192;
  bf16_t* O = (mod ? o_flow : o_rgb) + (size_t)(nn * NH + h) * Tdim * DH;

  __shared__ float sq[4][64];
  __shared__ __align__(128) bf16_t Alds[64 * 256]; // 32KB; [0,16K)=W dbuf,
                                                   // [16K,24K)=Ach dbuf during
                                                   // the K-loop (dead until
                                                   // the fused GEMM).
  char* WdB  = (char*)Alds;          // W dbuf: b*8192 bytes, 8KB each
  bf16_t* AchR = Alds + 8192;        // Ach dbuf: b*2048 elems, 4KB each

  const int tid = threadIdx.x;
  const int lane = tid & 63, wv = tid >> 6;
  const int g = lane >> 4, ln = lane & 15;

  f32x4 acc[4][4] = {};   // [mi][f]: rows t0+mi*16+4g+r, cols wv*64+f*16+ln
  const int akk = tid >> 3, atoff = (tid & 7) * 8;

  // stage W tile kb into buffer b via async DMA (2 x 16B per thread, linear)
  auto stageW = [&](int b, int kb) {
    const char* ws = (const char*)(Wb + (size_t)kb * 8192);
#pragma unroll
    for (int j = 0; j < 2; ++j)
      gload16(ws + j * 4096 + wv * 1024 /*+lane*16 by HW src calc*/ +
                  (lane * 16),
              WdB + b * 8192 + j * 4096 + wv * 1024);
  };

  // stage X chunk kb into Ach buffer b (f32 loads -> bf16 -> LDS)
  auto stageX = [&](int b, int kb) {
    const float* srcx = X + (size_t)(kb * 32 + akk) * Tdim + atoff;
    float4 f0 = *(const float4*)srcx;
    float4 f1 = *(const float4*)(srcx + 4);
    bf16x8 v = {(bf16_t)f0.x, (bf16_t)f0.y, (bf16_t)f0.z, (bf16_t)f0.w,
                (bf16_t)f1.x, (bf16_t)f1.y, (bf16_t)f1.z, (bf16_t)f1.w};
    *(bf16x8*)&AchR[b * 2048 + (atoff >> 4) * 512 + akk * 16 + (atoff & 15)] = v;
  };

  stageW(0, 0);
  __builtin_amdgcn_sched_barrier(0);
  stageX(0, 0);
  __syncthreads();           // drains DMA (vmcnt) + LDS writes (lgkm)

  int cur = 0;
  for (int kb = 0; kb < 32; ++kb) {
    if (kb + 1 < 32) {       // stage next step: DMA first (stays in flight
      stageW(cur ^ 1, kb + 1);           //  across the X-load vmcnt wait)
      __builtin_amdgcn_sched_barrier(0);
      stageX(cur ^ 1, kb + 1);
    }

    bf16x4 alo[4], ahi[4];
#pragma unroll
    for (int mi = 0; mi < 4; ++mi)
      tr_pair(&AchR[cur * 2048 + mi * 512], lane, alo[mi], ahi[mi]);
    bf16x8 wf[4];
#pragma unroll
    for (int f = 0; f < 4; ++f)
      wf[f] = *(const bf16x8*)(WdB + cur * 8192 + (wv * 4 + f) * 1024 +
                               lane * 16);
    lgkm0_fence();
#pragma unroll
    for (int mi = 0; mi < 4; ++mi) {
      bf16x8 a = cmb(alo[mi], ahi[mi]);
#pragma unroll
      for (int f = 0; f < 4; ++f) acc[mi][f] = mm16(a, wf[f], acc[mi][f]);
    }
    __syncthreads();         // next-step buffers landed; all waves done w/ cur
    cur ^= 1;
  }

  // row L2 norms
  float inv[4][4];
#pragma unroll
  for (int mi = 0; mi < 4; ++mi)
#pragma unroll
    for (int r = 0; r < 4; ++r) {
      float s = 0.f;
#pragma unroll
      for (int f = 0; f < 4; ++f) { float v = acc[mi][f][r]; s += v * v; }
      s += __shfl_xor(s, 1); s += __shfl_xor(s, 2);
      s += __shfl_xor(s, 4); s += __shfl_xor(s, 8);
      if (ln == 0) sq[wv][mi * 16 + 4 * g + r] = s;
    }
  __syncthreads();
#pragma unroll
  for (int mi = 0; mi < 4; ++mi)
#pragma unroll
    for (int r = 0; r < 4; ++r) {
      int rl = mi * 16 + 4 * g + r;
      float s = sq[0][rl] + sq[1][rl] + sq[2][rl] + sq[3][rl];
      inv[mi][r] = 1.0f / fmaxf(sqrtf(s), 1e-12f);
    }
  __syncthreads();           // everyone done reading sq / W+Ach regions

  // write O (global) and, for mod==0, the same values into swizzled Alds
#pragma unroll
  for (int mi = 0; mi < 4; ++mi)
#pragma unroll
    for (int f = 0; f < 4; ++f)
#pragma unroll
      for (int r = 0; r < 4; ++r) {
        bf16_t val = (bf16_t)(acc[mi][f][r] * inv[mi][r]);
        int row = mi * 16 + 4 * g + r;
        int col = wv * 64 + f * 16 + ln;
        O[(size_t)(t0 + row) * DH + col] = val;
        if (mod == 0)
          *(bf16_t*)((char*)Alds + ((row * 512 + col * 2) ^ ((row & 7) << 4))) = val;
      }

  if (mod != 0) return;

  // ---- fused kmatA: A = o_rgb(this tile) @ atte_w -> Aout ----
  __syncthreads();
  bf16_t* Ao = Aout + (size_t)(nn * NH + h) * Tdim * DH;
  f32x4 acc2[4][4] = {};
  for (int kb = 0; kb < 8; ++kb) {
    bf16x8 af[4];
#pragma unroll
    for (int mi = 0; mi < 4; ++mi) {
      int row = mi * 16 + ln;
      af[mi] = *(const bf16x8*)((const char*)Alds +
               ((row * 512 + kb * 64 + g * 16) ^ ((row & 7) << 4)));
    }
    bf16x8 wf[4];
    const bf16_t* wt = Wa + (size_t)(h * 8 + kb) * 8192 + (wv * 4) * 512 + lane * 8;
#pragma unroll
    for (int f = 0; f < 4; ++f) wf[f] = *(const bf16x8*)(wt + f * 512);
#pragma unroll
    for (int mi = 0; mi < 4; ++mi)
#pragma unroll
      for (int f = 0; f < 4; ++f) acc2[mi][f] = mm16(af[mi], wf[f], acc2[mi][f]);
  }
#pragma unroll
  for (int mi = 0; mi < 4; ++mi)
#pragma unroll
    for (int f = 0; f < 4; ++f)
#pragma unroll
      for (int r = 0; r < 4; ++r)
        Ao[(size_t)(t0 + mi * 16 + 4 * g + r) * DH + wv * 64 + f * 16 + ln] =
            (bf16_t)acc2[mi][f][r];
}

// ---------------------------------------------------------------------------
// kflash: both flash passes + epilogue.  grid 1024, block 256 (4 waves).
// bid -> p = (bid&7)*16 + (bid>>6), qx = (bid>>3)&7; 128 q-rows per block
// (32/wave, 2 row-groups).  s-tile = 32.
// K+V double-buffered in LDS via global_load_lds (no VMEM in compute ->
// vmcnt drains only at the tile barrier; true prefetch).  Swapped QK^T
// (mm16(K,Q)) keeps P in registers: lane q-row = rg*16+ln, s = nf*16+4g+r
// == kappa_tr A-frag slots for PV.  No-max softmax: P = exp(S-8).
// Epilogue: fast tanh-form GELU + fast tanh.  (Byte-identical to R10.)
// ---------------------------------------------------------------------------
__global__ __launch_bounds__(256, 2)
void kflash(const bf16_t* __restrict__ o_rgb, const bf16_t* __restrict__ o_flow,
            const bf16_t* __restrict__ Aw,
            const float* __restrict__ rgb, const float* __restrict__ flow,
            float* __restrict__ out) {
  const int bid = blockIdx.x;
  const int p  = (bid & 7) * 16 + (bid >> 6);   // bijective, XCD-chunked
  const int qx = (bid >> 3) & 7;
  const int nn = p >> 3, h = (p >> 1) & 3, pass = p & 1;
  const int t0 = qx * 128;
  const size_t nhoff = (size_t)(nn * NH + h) * Tdim * DH;
  const bf16_t* Qp = (pass ? o_flow : Aw) + nhoff;
  const bf16_t* Kp = (pass ? Aw : o_flow) + nhoff;
  const bf16_t* Vp = (pass ? o_flow : o_rgb) + nhoff;
  const float*  Xr = (pass ? flow : rgb) + (size_t)nn * Ddim * Tdim;
  float* Op = out + (size_t)pass * NB * Ddim * Tdim + (size_t)nn * Ddim * Tdim;

  __shared__ __align__(128) bf16_t Klds[2][32 * 256];  // 2x16KB, XOR-swizzled
  __shared__ __align__(128) bf16_t Vch [2][32 * 256];  // 2x16KB, [ech][k(32)][16]

  const int tid = threadIdx.x;
  const int lane = tid & 63, wv = tid >> 6;            // wv 0..3
  const int g = lane >> 4, ln = lane & 15;

  // Q fragments (kappa': contiguous 16B), rows t0 + wv*32 + rg*16 + ln.
  // Used as the B operand of the swapped QK^T (B col = lane&15 = q-row).
  bf16x8 qf[2][8];
#pragma unroll
  for (int rg = 0; rg < 2; ++rg) {
    const bf16_t* qrow = Qp + (size_t)(t0 + wv * 32 + rg * 16 + ln) * DH;
#pragma unroll
    for (int ks = 0; ks < 8; ++ks)
      qf[rg][ks] = *(const bf16x8*)(qrow + ks * 32 + 8 * g);
  }

  // async stage of one 32-row K/V tile into buffer b (8 chunks per thread).
  // K: linear LDS dest, pre-swizzled global source (involutive XOR of byte
  //    bits 4-6 with row bits 9-11).  V: chunked source (row stride 512B,
  //    16B chunks), linear dest.  LDS dest: wave-uniform base + lane*16.
  auto stage = [&](int b, int s0) {
    const char* Ks = (const char*)Kp + (size_t)s0 * 512;
    const char* Vs = (const char*)Vp + (size_t)s0 * 512;
    char* Kd = (char*)&Klds[b][0] + wv * 1024;
    char* Vd = (char*)&Vch[b][0] + wv * 1024;
#pragma unroll
    for (int j = 0; j < 4; ++j) {
      int gc = j * 256 + tid;                    // 16B chunk index, 0..1023
      int d  = gc * 16;
      gload16(Ks + (d ^ (((d >> 9) & 7) << 4)), Kd + j * 4096);
      int ech = gc >> 6, kk = (gc & 63) >> 1, half = gc & 1;
      gload16(Vs + kk * 512 + (ech * 2 + half) * 16, Vd + j * 4096);
    }
  };

  f32x4 eacc[2][16] = {};
  float l_par[2] = {0.f, 0.f};

  stage(0, 0);
  __syncthreads();           // vmcnt(0) drain + barrier: tile 0 visible

  int cur = 0;
  for (int s0 = 0; s0 < Tdim; s0 += 32) {
    if (s0 + 32 < Tdim) stage(cur ^ 1, s0 + 32);   // async, flies under compute

    // S^T = K Q^T (swapped): K frags from LDS as the A operand
    // (A row = lane&15 = s-row within nf block, k = ks*32 + 8g + i).
    // Result: lane holds q-row = rg*16 + ln, s = nf*16 + 4g + r.
    f32x4 sacc[2][2] = {};
#pragma unroll
    for (int ks = 0; ks < 8; ++ks) {
      int row0 = ln, row1 = 16 + ln;
      bf16x8 kf0 = *(const bf16x8*)((const char*)&Klds[cur][0] +
          ((row0 * 512 + ks * 64 + g * 16) ^ ((row0 & 7) << 4)));
      bf16x8 kf1 = *(const bf16x8*)((const char*)&Klds[cur][0] +
          ((row1 * 512 + ks * 64 + g * 16) ^ ((row1 & 7) << 4)));
      sacc[0][0] = mm16(kf0, qf[0][ks], sacc[0][0]);
      sacc[1][0] = mm16(kf0, qf[1][ks], sacc[1][0]);
      sacc[0][1] = mm16(kf1, qf[0][ks], sacc[0][1]);
      sacc[1][1] = mm16(kf1, qf[1][ks], sacc[1][1]);
    }

    // P = exp(S - 8) fully in-register.  Slot set per lane:
    // lo j: s = 4g+j (nf=0, r=j), hi j: s = 16+4g+j (nf=1) == kappa_tr A-frag.
    bf16x8 pa[2];
#pragma unroll
    for (int rg = 0; rg < 2; ++rg) {
      bf16x4 lo, hi;
#pragma unroll
      for (int r = 0; r < 4; ++r) {
        float p0 = __expf(sacc[rg][0][r] - 8.0f);
        float p1 = __expf(sacc[rg][1][r] - 8.0f);
        l_par[rg] += p0 + p1;
        lo[r] = (bf16_t)p0;
        hi[r] = (bf16_t)p1;
      }
      pa[rg] = cmb(lo, hi);
    }

    // E += P @ V  (P in registers; V via tr-read, shared by both rg)
#pragma unroll
    for (int nb4 = 0; nb4 < 4; ++nb4) {
      bf16x4 vlo[4], vhi[4];
#pragma unroll
      for (int j = 0; j < 4; ++j)
        tr_pair(&Vch[cur][(nb4 * 4 + j) * 512], lane, vlo[j], vhi[j]);
      lgkm0_fence();
#pragma unroll
      for (int j = 0; j < 4; ++j) {
        bf16x8 vf = cmb(vlo[j], vhi[j]);
        eacc[0][nb4 * 4 + j] = mm16(pa[0], vf, eacc[0][nb4 * 4 + j]);
        eacc[1][nb4 * 4 + j] = mm16(pa[1], vf, eacc[1][nb4 * 4 + j]);
      }
    }

    __syncthreads();         // next tile landed; all waves done with cur
    cur ^= 1;
  }

  // epilogue: reduce l (lanes ln,16+ln,32+ln,48+ln cover all 32 s), fetch
  // per-output-row invl via width-16 shfl, fast gelu, residual, fast tanh.
  float invl[2][4];
#pragma unroll
  for (int rg = 0; rg < 2; ++rg) {
    float l = l_par[rg];
    l += __shfl_xor(l, 16); l += __shfl_xor(l, 32);
    // every lane now holds the total for q-row rg*16 + ln
#pragma unroll
    for (int r = 0; r < 4; ++r)
      invl[rg][r] = 1.0f / __shfl(l, 4 * g + r, 16);
  }
#pragma unroll
  for (int rg = 0; rg < 2; ++rg)
#pragma unroll
    for (int nb = 0; nb < 16; ++nb)
#pragma unroll
      for (int r = 0; r < 4; ++r) {
        float e = eacc[rg][nb][r] * invl[rg][r];
        // tanh-form GELU (|e| small -> approx error < 2e-4)
        float u = 0.79788456f * (e + 0.044715f * e * e * e);
        float ge = 0.5f * e * (1.0f + ftanh(u));
        int trow = t0 + wv * 32 + rg * 16 + 4 * g + r;
        int col = h * 256 + nb * 16 + ln;
        size_t idx = (size_t)trow * Tdim + col;
        Op[idx] = ftanh(ge + Xr[idx]);
      }
}

// ---------------------------------------------------------------------------
extern "C" void kernel_launch(void* const* d_in, const int* in_sizes, int n_in,
                              void* d_out, int out_size, void* d_ws, size_t ws_size,
                              hipStream_t stream) {
  const float* rgb   = (const float*)d_in[0];
  const float* flow  = (const float*)d_in[1];
  const float* rgbp  = (const float*)d_in[2];
  const float* flowp = (const float*)d_in[3];
  const float* attw  = (const float*)d_in[4];
  float* out = (float*)d_out;

  const size_t OSZ = (size_t)NB * NH * Tdim * DH;   // 16.7M bf16
  bf16_t* o_rgb  = (bf16_t*)d_ws;                   // 32 MB
  bf16_t* o_flow = o_rgb + OSZ;                     // 32 MB
  bf16_t* Aw     = o_flow + OSZ;                    // 32 MB
  bf16_t* Wl     = Aw + OSZ;                        // 4 MB (2M elems)
  bf16_t* Wa     = Wl + (size_t)2 * NH * 32 * 8192; // 0.5 MB

  kconvW<<<1152, 256, 0, stream>>>(rgbp, flowp, attw, Wl, Wa);
  kproj<<<dim3(16, 4, 32), 256, 0, stream>>>(rgb, flow, Wl, Wa,
                                             o_rgb, o_flow, Aw);
  kflash<<<1024, 256, 0, stream>>>(o_rgb, o_flow, Aw, rgb, flow, out);
}